// Round 15
// baseline (9689.522 us; speedup 1.0000x reference)
//
#include <hip/hip_runtime.h>
#include <math.h>

// Problem constants
#define BB   64
#define SS   256
#define ED   300
#define EDP  304    // padded K for input projection (zeros in 300..303)
#define HH   512
#define G3   1536   // 3*H (one direction)
#define ATT_ 256
#define BS_  16384  // BB*SS
#define CHK  64     // timesteps per chunk
#define NCHK 4

// ---------------------------------------------------------------------------
// K1: embedding gather + max-norm renorm.  one block per (b,s) row, 128 thr.
// ---------------------------------------------------------------------------
__global__ void k_embed(const int* __restrict__ x, const float* __restrict__ emb,
                        float* __restrict__ e) {
    int row = blockIdx.x;
    int tok = x[row];
    const float* src = emb + (size_t)tok * ED;
    float* dst = e + (size_t)row * EDP;
    int tid = threadIdx.x;  // 128
    float v[3];
    float ss = 0.f;
#pragma unroll
    for (int i = 0; i < 3; ++i) {
        int k = tid + i * 128;
        float t = (k < ED) ? src[k] : 0.f;
        v[i] = t;
        ss += t * t;
    }
    for (int off = 32; off > 0; off >>= 1) ss += __shfl_xor(ss, off, 64);
    __shared__ float red[2];
    if ((tid & 63) == 0) red[tid >> 6] = ss;
    __syncthreads();
    float nrm = sqrtf(red[0] + red[1]);
    float scale = fminf(1.0f, 5.0f / (nrm + 1e-7f));
#pragma unroll
    for (int i = 0; i < 3; ++i) {
        int k = tid + i * 128;
        if (k < EDP) dst[k] = (k < ED) ? v[i] * scale : 0.f;
    }
}

// ---------------------------------------------------------------------------
// kq schedule shared by pack and GRU kernel (3-gate-per-thread layout):
// thread t: u = t>>3 (unit), ks = t&7 (k-slice).
//  m = 0,1   : kq = oc*16 + 2*ks + m            (own-unit quads, phase A)
//  m = 2..15 : kq = (oc*16 + 16 + ks*14 + (m-2)) & 127
// ---------------------------------------------------------------------------
__host__ __device__ __forceinline__ int kq_of(int oc, int ks, int m) {
    return (m < 2) ? (oc * 16 + 2 * ks + m)
                   : ((oc * 16 + 16 + ks * 14 + (m - 2)) & 127);
}

// ---------------------------------------------------------------------------
// K_prep_all: one launch builds every preprocessed weight buffer.
//  seg0: Wtc[EDP][3072]  = [Wihf^T | Wihb^T]  (rows 300..303 zero)
//  seg1: bcc[3072]       = [bihf | bihb]
//  seg2: W1at[1024][256] = W1[:, :1024]^T
//  seg3: Wq (both dirs)  = eighth-split register-resident Whh pack:
//        per-dir [oc 0..7][m 0..15][g 0..2][t 0..511][e 0..3];
//        t: u = t>>3, ks = t&7; unit uu = oc*64+u; kq = kq_of(oc, ks, m);
//        value = Whh[(g*512+uu)*512 + kq*4 + e]
// ---------------------------------------------------------------------------
#define PN0 933888            // 304*3072
#define PN1 (PN0 + 3072)
#define PN2 (PN1 + 262144)
#define PN3 (PN2 + 1572864)   // 2*786432

__global__ void k_prep_all(const float* __restrict__ Wihf, const float* __restrict__ Wihb,
                           const float* __restrict__ bihf, const float* __restrict__ bihb,
                           const float* __restrict__ W1,
                           const float* __restrict__ Whhf, const float* __restrict__ Whhb,
                           float* __restrict__ Wtc, float* __restrict__ bcc,
                           float* __restrict__ W1at, float* __restrict__ Wq) {
    int idx = blockIdx.x * blockDim.x + threadIdx.x;
    int stride = gridDim.x * blockDim.x;
    for (int i = idx; i < PN3; i += stride) {
        if (i < PN0) {
            int k = i / 3072, n = i - k * 3072;
            int dir = n >= 1536, nn = n - dir * 1536;
            const float* Wih = dir ? Wihb : Wihf;
            Wtc[i] = (k < ED) ? Wih[(size_t)nn * ED + k] : 0.f;
        } else if (i < PN1) {
            int j = i - PN0;
            bcc[j] = (j < 1536) ? bihf[j] : bihb[j - 1536];
        } else if (i < PN2) {
            int j = i - PN1;
            int n = j >> 10, k = j & 1023;
            W1at[(size_t)k * ATT_ + n] = W1[(size_t)n * 2048 + k];
        } else {
            int j = i - PN2;
            int dir = j / 786432, jj = j - dir * 786432;
            const float* Whh = dir ? Whhb : Whhf;
            int oc  = jj / 98304;
            int rem = jj - oc * 98304;
            int m   = rem / 6144;          // 3*512*4
            int r3  = rem - m * 6144;
            int g   = r3 / 2048;           // 512*4
            int r4  = r3 - g * 2048;
            int t   = r4 >> 2;
            int e   = r4 & 3;
            int u   = t >> 3;
            int ks  = t & 7;
            int kq  = kq_of(oc, ks, m);
            Wq[j] = Whh[((size_t)(g * 512 + oc * 64 + u)) * 512 + kq * 4 + e];
        }
    }
}

// ---------------------------------------------------------------------------
// fp32 GEMM, 128x128 tile, 256 threads, 8x8 per thread (round-12, proven).
// ---------------------------------------------------------------------------
#define BSKEW(n) ((n) + (((n) >> 5) << 2))

template <int KT, int EPI>
__global__ void __launch_bounds__(256) k_gemm128(
    const float* __restrict__ A, int lda, long strideA,
    const float* __restrict__ Bm, int ldb, long strideB,
    float* __restrict__ C, int ldc, long strideC,
    int M, int N, int K,
    const float* __restrict__ bias, const float* __restrict__ bias2,
    int spos0, int spos1) {
    __shared__ float As[KT * 132];
    __shared__ float Bs[KT * 144];
    const int tid = threadIdx.x;
    const int tx = tid & 15, ty = tid >> 4;
    const int mbase = blockIdx.y * 128, nbase = blockIdx.x * 128;
    const int spos = (spos0 >= 0 && nbase >= 1536) ? spos1 : spos0;
    const float* Ab = A + (long)blockIdx.z * strideA;
    const float* Bb = Bm + (long)blockIdx.z * strideB;
    float* Cb = C + (long)blockIdx.z * strideC;
    float acc[8][8] = {};
    const int bgrp = tx * 8 + ((tx >> 2) << 2);
    for (int k0 = 0; k0 < K; k0 += KT) {
#pragma unroll
        for (int t = 0; t < 2; ++t) {          // A: 512 float4s, 2/thread
            int f = tid * 2 + t;
            int r = f >> 2, c4 = f & 3;
            int row = mbase + r;
            int arow = (spos >= 0) ? ((row >> 6) * 256 + spos + (row & 63)) : row;
            float4 a = *(const float4*)&Ab[(size_t)arow * lda + k0 + c4 * 4];
            As[(c4 * 4 + 0) * 132 + r] = a.x;
            As[(c4 * 4 + 1) * 132 + r] = a.y;
            As[(c4 * 4 + 2) * 132 + r] = a.z;
            As[(c4 * 4 + 3) * 132 + r] = a.w;
        }
#pragma unroll
        for (int t = 0; t < 2; ++t) {          // B: 512 float4s, 2/thread
            int f = tid * 2 + t;
            int kk = f >> 5, n = (f & 31) * 4;
            float4 b = *(const float4*)&Bb[(size_t)(k0 + kk) * ldb + nbase + n];
            *(float4*)&Bs[kk * 144 + BSKEW(n)] = b;
        }
        __syncthreads();
#pragma unroll
        for (int kk = 0; kk < KT; ++kk) {
            const float4* pa = (const float4*)&As[kk * 132 + ty * 8];
            float4 a0 = pa[0], a1 = pa[1];
            const float4* pb = (const float4*)&Bs[kk * 144 + bgrp];
            float4 b0 = pb[0], b1 = pb[1];
            float av[8] = {a0.x, a0.y, a0.z, a0.w, a1.x, a1.y, a1.z, a1.w};
            float bv[8] = {b0.x, b0.y, b0.z, b0.w, b1.x, b1.y, b1.z, b1.w};
#pragma unroll
            for (int i = 0; i < 8; ++i)
#pragma unroll
                for (int j = 0; j < 8; ++j) acc[i][j] += av[i] * bv[j];
        }
        __syncthreads();
    }
    if (EPI == 3) {
        const int row0 = mbase + ty * 8;
        const size_t bb = (size_t)(row0 >> 8) * strideC;
#pragma unroll
        for (int j = 0; j < 8; ++j) {
            int col = nbase + tx * 8 + j;
            float vj[8];
#pragma unroll
            for (int i = 0; i < 8; ++i) {
                int row = row0 + i;
                vj[i] = tanhf(acc[i][j] + bias2[(size_t)(row >> 8) * ATT_ + col]);
            }
            float* cp = &Cb[bb + (size_t)col * ldc + (row0 & 255)];
            ((float4*)cp)[0] = make_float4(vj[0], vj[1], vj[2], vj[3]);
            ((float4*)cp)[1] = make_float4(vj[4], vj[5], vj[6], vj[7]);
        }
    } else {
#pragma unroll
        for (int i = 0; i < 8; ++i) {
            int row = mbase + ty * 8 + i;
            float vout[8];
#pragma unroll
            for (int j = 0; j < 8; ++j) {
                int col = nbase + tx * 8 + j;
                float v = acc[i][j];
                if (EPI == 1) v += bias[col];
                if (EPI == 2) v = tanhf(v + bias2[(size_t)(row >> 8) * ATT_ + col]);
                vout[j] = v;
            }
            float4* cp = (float4*)&Cb[(size_t)row * ldc + nbase + tx * 8];
            cp[0] = make_float4(vout[0], vout[1], vout[2], vout[3]);
            cp[1] = make_float4(vout[4], vout[5], vout[6], vout[7]);
        }
    }
}

// ---------------------------------------------------------------------------
// GRU helpers
// ---------------------------------------------------------------------------
__device__ __forceinline__ float sigmoidf_(float v) { return 1.f / (1.f + expf(-v)); }

// one k-quad, 3 gates x 4 batches, weights from registers (static index)
#define RFMA(mm, kv)                                                        \
    {                                                                       \
        float4 h0 = hs4[kv];                                                \
        float4 h1 = hs4[128 + (kv)];                                        \
        float4 h2 = hs4[256 + (kv)];                                        \
        float4 h3 = hs4[384 + (kv)];                                        \
        float4 w = wreg[(mm) * 3 + 0];                                      \
        a0[0] += h0.x*w.x + h0.y*w.y + h0.z*w.z + h0.w*w.w;                 \
        a0[1] += h1.x*w.x + h1.y*w.y + h1.z*w.z + h1.w*w.w;                 \
        a0[2] += h2.x*w.x + h2.y*w.y + h2.z*w.z + h2.w*w.w;                 \
        a0[3] += h3.x*w.x + h3.y*w.y + h3.z*w.z + h3.w*w.w;                 \
        w = wreg[(mm) * 3 + 1];                                             \
        a1[0] += h0.x*w.x + h0.y*w.y + h0.z*w.z + h0.w*w.w;                 \
        a1[1] += h1.x*w.x + h1.y*w.y + h1.z*w.z + h1.w*w.w;                 \
        a1[2] += h2.x*w.x + h2.y*w.y + h2.z*w.z + h2.w*w.w;                 \
        a1[3] += h3.x*w.x + h3.y*w.y + h3.z*w.z + h3.w*w.w;                 \
        w = wreg[(mm) * 3 + 2];                                             \
        a2[0] += h0.x*w.x + h0.y*w.y + h0.z*w.z + h0.w*w.w;                 \
        a2[1] += h1.x*w.x + h1.y*w.y + h1.z*w.z + h1.w*w.w;                 \
        a2[2] += h2.x*w.x + h2.y*w.y + h2.z*w.z + h2.w*w.w;                 \
        a2[3] += h3.x*w.x + h3.y*w.y + h3.z*w.z + h3.w*w.w;                 \
    }

// ---------------------------------------------------------------------------
// Eighth-split, 4-batch GRU with REGISTER-RESIDENT weights.
// 256 blocks x 512 threads = group(16) x dir(2) x oc(8); thread = (u:64, ks:8).
// Each thread holds all 3 gate rows of unit oc*64+u for its 16-quad k-slice
// in wreg[48] (192 VGPR), loaded once per chunk -> ZERO weight traffic per
// step.  8-lane shfl delivers (hr,hz,hn) to the ks==0 thread, which does the
// gate update directly (gact buffer eliminated).  Exchange protocol is the
// round-8-validated relaxed/release scheme, mapping identical to round 12/14.
// ---------------------------------------------------------------------------
__global__ void __launch_bounds__(512)
k_gru_reg(const float* __restrict__ xw,    // [4096][3072], dir offset *1536
          const float* __restrict__ Wq,    // [dir][oc][m][g][t][e]
          const float* __restrict__ bhhf, const float* __restrict__ bhhb,
          float* __restrict__ h_all,
          float* __restrict__ hx,          // [parity][dir][group][bb][512]
          unsigned* __restrict__ flg,      // ((dir*16+group)*8+oc)*32
          int c) {
    const int bid   = blockIdx.x;
    const int group = bid >> 4;
    const int dir   = (bid >> 3) & 1;
    const int oc    = bid & 7;
    const int tid   = threadIdx.x;     // 512
    const int u     = tid >> 3;        // 0..63
    const int ks    = tid & 7;
    const int ug    = oc * 64 + u;
    const float* __restrict__ bhh = dir ? bhhb : bhhf;
    __shared__ __align__(16) float hs[2048];   // [bb][512]

    // weights -> registers (48 float4 / thread, coalesced loads)
    const float4* __restrict__ wp =
        (const float4*)Wq + (size_t)(dir * 8 + oc) * 24576 + tid;
    float4 wreg[48];
#pragma unroll
    for (int i = 0; i < 48; ++i) wreg[i] = wp[(size_t)i * 512];

    if (c == 0) {
        for (int t = tid; t < 2048; t += 512) hs[t] = 0.f;
    } else {
        const int prevpos = dir ? (256 - CHK * c) : (CHK * c - 1);
        for (int t = tid; t < 2048; t += 512) {
            int bb = t >> 9, uu = t & 511;
            hs[t] = h_all[((size_t)(group * 4 + bb) * 256 + prevpos) * 1024 +
                          dir * 512 + uu];
        }
    }
    float b0 = 0.f, b1 = 0.f, b2 = 0.f;
    if (ks == 0) { b0 = bhh[ug]; b1 = bhh[512 + ug]; b2 = bhh[1024 + ug]; }
    const int fbase = (dir * 16 + group) * 8;
    const int fi = (fbase + oc) * 32;
    __syncthreads();
    const float4* __restrict__ hs4 = (const float4*)hs;

    for (int j = 0; j < CHK; ++j) {
        const int gi  = c * CHK + j;
        const int pos = dir ? (255 - gi) : gi;
        // --- poll 7 sibling flags, then issue partner h loads (1792 vals) ---
        float ph0 = 0.f, ph1 = 0.f, ph2 = 0.f, ph3 = 0.f;
        if (j > 0) {
            if (tid < 7) {
                const unsigned* f = &flg[(fbase + ((oc + 1 + tid) & 7)) * 32];
                while (__hip_atomic_load(f, __ATOMIC_RELAXED,
                                         __HIP_MEMORY_SCOPE_AGENT) < (unsigned)gi)
                    __builtin_amdgcn_s_sleep(1);
            }
            __syncthreads();
            const float* hxb = hx + (((size_t)((gi - 1) & 1) * 2 + dir) * 16 +
                                     group) * 2048;
            {
                int i0 = tid;
                int bb = i0 / 448, pi = i0 - bb * 448;
                int pu = pi + ((pi >= oc * 64) ? 64 : 0);
                ph0 = __hip_atomic_load(&hxb[bb * 512 + pu], __ATOMIC_RELAXED,
                                        __HIP_MEMORY_SCOPE_AGENT);
                int i1 = tid + 512;
                bb = i1 / 448; pi = i1 - bb * 448;
                pu = pi + ((pi >= oc * 64) ? 64 : 0);
                ph1 = __hip_atomic_load(&hxb[bb * 512 + pu], __ATOMIC_RELAXED,
                                        __HIP_MEMORY_SCOPE_AGENT);
                int i2 = tid + 1024;
                bb = i2 / 448; pi = i2 - bb * 448;
                pu = pi + ((pi >= oc * 64) ? 64 : 0);
                ph2 = __hip_atomic_load(&hxb[bb * 512 + pu], __ATOMIC_RELAXED,
                                        __HIP_MEMORY_SCOPE_AGENT);
                if (tid < 256) {
                    int i3 = tid + 1536;
                    bb = i3 / 448; pi = i3 - bb * 448;
                    pu = pi + ((pi >= oc * 64) ? 64 : 0);
                    ph3 = __hip_atomic_load(&hxb[bb * 512 + pu], __ATOMIC_RELAXED,
                                            __HIP_MEMORY_SCOPE_AGENT);
                }
            }
        }
        // --- matvec: 3 gates x own unit x K-slice x 4 batches ---
        float a0[4] = {0.f, 0.f, 0.f, 0.f};
        float a1[4] = {0.f, 0.f, 0.f, 0.f};
        float a2[4] = {0.f, 0.f, 0.f, 0.f};
        if (gi > 0) {
            if (j > 0) {
                RFMA(0, oc * 16 + 2 * ks);       // phase A: own-unit quads
                RFMA(1, oc * 16 + 2 * ks + 1);
                {   // deposit partner h
                    int i0 = tid;
                    int bb = i0 / 448, pi = i0 - bb * 448;
                    int pu = pi + ((pi >= oc * 64) ? 64 : 0);
                    hs[bb * 512 + pu] = ph0;
                    int i1 = tid + 512;
                    bb = i1 / 448; pi = i1 - bb * 448;
                    pu = pi + ((pi >= oc * 64) ? 64 : 0);
                    hs[bb * 512 + pu] = ph1;
                    int i2 = tid + 1024;
                    bb = i2 / 448; pi = i2 - bb * 448;
                    pu = pi + ((pi >= oc * 64) ? 64 : 0);
                    hs[bb * 512 + pu] = ph2;
                    if (tid < 256) {
                        int i3 = tid + 1536;
                        bb = i3 / 448; pi = i3 - bb * 448;
                        pu = pi + ((pi >= oc * 64) ? 64 : 0);
                        hs[bb * 512 + pu] = ph3;
                    }
                }
                __syncthreads();
                int kq = (oc * 16 + 16 + ks * 14) & 127;
#pragma unroll
                for (int m = 2; m < 16; ++m) { RFMA(m, kq); kq = (kq + 1) & 127; }
            } else {
                RFMA(0, oc * 16 + 2 * ks);
                RFMA(1, oc * 16 + 2 * ks + 1);
                int kq = (oc * 16 + 16 + ks * 14) & 127;
#pragma unroll
                for (int m = 2; m < 16; ++m) { RFMA(m, kq); kq = (kq + 1) & 127; }
            }
            // reduce across the 8 k-slices (lanes u*8+ks share a wave)
#pragma unroll
            for (int bb = 0; bb < 4; ++bb) {
                a0[bb] += __shfl_xor(a0[bb], 1, 64);
                a0[bb] += __shfl_xor(a0[bb], 2, 64);
                a0[bb] += __shfl_xor(a0[bb], 4, 64);
                a1[bb] += __shfl_xor(a1[bb], 1, 64);
                a1[bb] += __shfl_xor(a1[bb], 2, 64);
                a1[bb] += __shfl_xor(a1[bb], 4, 64);
                a2[bb] += __shfl_xor(a2[bb], 1, 64);
                a2[bb] += __shfl_xor(a2[bb], 2, 64);
                a2[bb] += __shfl_xor(a2[bb], 4, 64);
            }
        }
        __syncthreads();   // all hs reads done before gate threads write hs
        // --- gate update (ks==0 threads: 4 batches x own unit) ---
        if (ks == 0) {
#pragma unroll
            for (int bb = 0; bb < 4; ++bb) {
                const int b = group * 4 + bb;
                const int crow = b * CHK + (dir ? (CHK - 1 - j) : j);
                const float* __restrict__ xrow =
                    xw + (size_t)crow * 3072 + dir * 1536;
                float xr = xrow[ug], xz = xrow[512 + ug], xn = xrow[1024 + ug];
                float rr = sigmoidf_(xr + b0 + a0[bb]);
                float zz = sigmoidf_(xz + b1 + a1[bb]);
                float nn = tanhf(xn + rr * (b2 + a2[bb]));
                float h = (1.f - zz) * nn + zz * hs[bb * 512 + ug];
                hs[bb * 512 + ug] = h;
                __hip_atomic_store(&h_all[((size_t)b * 256 + pos) * 1024 +
                                          dir * 512 + ug],
                                   h, __ATOMIC_RELAXED, __HIP_MEMORY_SCOPE_AGENT);
                __hip_atomic_store(&hx[(((size_t)(gi & 1) * 2 + dir) * 16 +
                                        group) * 2048 + bb * 512 + ug],
                                   h, __ATOMIC_RELAXED, __HIP_MEMORY_SCOPE_AGENT);
            }
        }
        __syncthreads();   // hx stores drained before release
        if (tid == 0)
            __hip_atomic_store(&flg[fi], (unsigned)(gi + 1), __ATOMIC_RELEASE,
                               __HIP_MEMORY_SCOPE_AGENT);
    }
}

// ---------------------------------------------------------------------------
// K_target_tmp2: fused span-mean + tmp2 projection.  one block per b.
// ---------------------------------------------------------------------------
__global__ void k_target_tmp2(const float* __restrict__ h_all,
                              const int* __restrict__ ts, const int* __restrict__ te,
                              const float* __restrict__ W1, const float* __restrict__ b1,
                              float* __restrict__ tmp2) {
    int b = blockIdx.x;
    int tid = threadIdx.x;  // 256
    __shared__ __align__(16) float tg[1024];
    int s0 = ts[b], s1 = te[b];
    float inv = 1.f / (float)(s1 - s0 + 1);
    for (int d = tid; d < 1024; d += 256) {
        float acc = 0.f;
        for (int s = s0; s <= s1; ++s) acc += h_all[((size_t)b * 256 + s) * 1024 + d];
        tg[d] = acc * inv;
    }
    __syncthreads();
    const float4* wrow = (const float4*)(W1 + (size_t)tid * 2048 + 1024);
    const float4* tg4 = (const float4*)tg;
    float acc = b1[tid];
    for (int k = 0; k < 256; ++k) {
        float4 w = wrow[k], t = tg4[k];
        acc += w.x * t.x + w.y * t.y + w.z * t.z + w.w * t.w;
    }
    tmp2[(size_t)b * ATT_ + tid] = acc;
}

// ---------------------------------------------------------------------------
// softmax over last axis, in place.  one block per (b,k) row of 256.
// ---------------------------------------------------------------------------
__global__ void k_softmax(float* __restrict__ beta) {
    int row = blockIdx.x;
    float* p = beta + (size_t)row * 256;
    int tid = threadIdx.x;  // 256
    float v = p[tid];
    float m = v;
    for (int off = 32; off > 0; off >>= 1) m = fmaxf(m, __shfl_xor(m, off, 64));
    __shared__ float red[4];
    if ((tid & 63) == 0) red[tid >> 6] = m;
    __syncthreads();
    m = fmaxf(fmaxf(red[0], red[1]), fmaxf(red[2], red[3]));
    float e = expf(v - m);
    float ssum = e;
    for (int off = 32; off > 0; off >>= 1) ssum += __shfl_xor(ssum, off, 64);
    __shared__ float red2[4];
    if ((tid & 63) == 0) red2[tid >> 6] = ssum;
    __syncthreads();
    float tot = red2[0] + red2[1] + red2[2] + red2[3];
    p[tid] = e / tot;
}

// ---------------------------------------------------------------------------
// final: out[row, 0:3] = result[row,:] . W2[l,:] + b2[l]
// ---------------------------------------------------------------------------
__global__ void k_final(const float* __restrict__ result, const float* __restrict__ W2,
                        const float* __restrict__ b2, float* __restrict__ out) {
    int row = blockIdx.x;
    int tid = threadIdx.x;  // 256
    const float* r = result + (size_t)row * 1024;
    float a0 = 0.f, a1 = 0.f, a2 = 0.f;
    for (int h = tid; h < 1024; h += 256) {
        float rv = r[h];
        a0 += rv * W2[h];
        a1 += rv * W2[1024 + h];
        a2 += rv * W2[2048 + h];
    }
    for (int off = 32; off > 0; off >>= 1) {
        a0 += __shfl_xor(a0, off, 64);
        a1 += __shfl_xor(a1, off, 64);
        a2 += __shfl_xor(a2, off, 64);
    }
    __shared__ float red[4][3];
    if ((tid & 63) == 0) {
        red[tid >> 6][0] = a0; red[tid >> 6][1] = a1; red[tid >> 6][2] = a2;
    }
    __syncthreads();
    if (tid < 3) {
        float s = red[0][tid] + red[1][tid] + red[2][tid] + red[3][tid];
        out[(size_t)row * 3 + tid] = s + b2[tid];
    }
}

// ---------------------------------------------------------------------------
extern "C" void kernel_launch(void* const* d_in, const int* in_sizes, int n_in,
                              void* d_out, int out_size, void* d_ws, size_t ws_size,
                              hipStream_t stream) {
    const int*   x      = (const int*)d_in[0];
    const int*   tstart = (const int*)d_in[1];
    const int*   tend   = (const int*)d_in[2];
    const float* emb    = (const float*)d_in[3];
    const float* Wihf   = (const float*)d_in[4];
    const float* Whhf   = (const float*)d_in[5];
    const float* bihf   = (const float*)d_in[6];
    const float* bhhf   = (const float*)d_in[7];
    const float* Wihb   = (const float*)d_in[8];
    const float* Whhb   = (const float*)d_in[9];
    const float* bihb   = (const float*)d_in[10];
    const float* bhhb   = (const float*)d_in[11];
    const float* W1     = (const float*)d_in[12];
    const float* b1     = (const float*)d_in[13];
    const float* u      = (const float*)d_in[14];
    const float* W2     = (const float*)d_in[15];
    const float* b2     = (const float*)d_in[16];
    float* out = (float*)d_out;
    float* ws = (float*)d_ws;

    // workspace layout (floats).  total = 43,236,512 floats = 172.9 MB
    float* h_p    = ws;                        // 16,777,216
    float* e_p    = h_p + 16777216;            // 4,980,736  (16384 x 304)
    float* xwc_p  = e_p + 4980736;             // 12,582,912 (chunk, both dirs)
    float* Wq_p   = xwc_p + 12582912;          // 1,572,864  (packed Whh, 2 dirs)
    float* Wtc_p  = Wq_p + 1572864;            // 933,888    (304 x 3072)
    float* pad_p  = Wtc_p + 933888;            // 1,700,000  (res alias headroom)
    float* bcc_p  = pad_p + 1700000;           // 3,072
    float* W1at_p = bcc_p + 3072;              // 262,144
    float* tg_p   = W1at_p + 262144;           // 65,536  (reserved, unused)
    float* t2_p   = tg_p + 65536;              // 16,384
    float* beta_p = t2_p + 16384;              // 4,194,304
    float* hx_p   = beta_p + 4194304;          // 131,072
    unsigned* flg_p = (unsigned*)(hx_p + 131072);  // 16,384 uints
    // aliases into dead-after-GRU regions:
    float* ot_p   = e_p;                       // 4,194,304 <= 4,980,736
    float* res_p  = xwc_p;                     // 16,777,216 <= xwc..pad

    if (ws_size < (size_t)43236512 * 4) return;  // refuse to overflow scratch

    // 0. zero pair flags (every call / graph replay)
    hipMemsetAsync(flg_p, 0, 16384 * sizeof(unsigned), stream);
    // 1. embedding + renorm (padded to 304 cols)
    k_embed<<<BS_, 128, 0, stream>>>(x, emb, e_p);
    // 2. all weight preps in one launch
    k_prep_all<<<1024, 256, 0, stream>>>(Wihf, Wihb, bihf, bihb, W1, Whhf, Whhb,
                                         Wtc_p, bcc_p, W1at_p, Wq_p);
    // 3. chunked: merged 2-dir input proj, then register-resident GRU
    for (int c = 0; c < NCHK; ++c) {
        k_gemm128<16, 1><<<dim3(24, 32, 1), 256, 0, stream>>>(
            e_p, EDP, 0, Wtc_p, 3072, 0, xwc_p, 3072, 0, BB * CHK, 3072, EDP,
            bcc_p, nullptr, CHK * c, 192 - CHK * c);
        k_gru_reg<<<256, 512, 0, stream>>>(xwc_p, Wq_p, bhhf, bhhb,
                                           h_p, hx_p, flg_p, c);
    }
    // 4. fused target span mean + tmp2
    k_target_tmp2<<<BB, 256, 0, stream>>>(h_p, tstart, tend, W1, b1, t2_p);
    // 5. o = tanh(h @ W1a^T + tmp2), written TRANSPOSED into ot[b][a][s]
    k_gemm128<16, 3><<<dim3(2, 128, 1), 256, 0, stream>>>(
        h_p, 1024, 0, W1at_p, ATT_, 0, ot_p, ATT_, 65536, BS_, ATT_, 1024,
        nullptr, t2_p, -1, -1);
    // 6. beta[b][k][s] = u @ ot[b]
    k_gemm128<16, 0><<<dim3(2, 2, BB), 256, 0, stream>>>(
        u, ATT_, 0, ot_p, ATT_, 65536, beta_p, ATT_, 65536, ATT_, ATT_, ATT_,
        nullptr, nullptr, -1, -1);
    // 7. softmax over s (in place)
    k_softmax<<<BS_, 256, 0, stream>>>(beta_p);
    // 8. result[b][k][h] = alfa[b] @ h[b]
    k_gemm128<16, 0><<<dim3(8, 2, BB), 256, 0, stream>>>(
        beta_p, ATT_, 65536, h_p, 1024, 262144, res_p, 1024, 262144,
        ATT_, 1024, ATT_, nullptr, nullptr, -1, -1);
    // 9. final linear
    k_final<<<BS_, 256, 0, stream>>>(res_p, W2, b2, out);
}

// Round 16
// 3181.113 us; speedup vs baseline: 3.0460x; 3.0460x over previous
//
#include <hip/hip_runtime.h>
#include <math.h>

// Problem constants
#define BB   64
#define SS   256
#define ED   300
#define EDP  304    // padded K for input projection (zeros in 300..303)
#define HH   512
#define G3   1536   // 3*H (one direction)
#define ATT_ 256
#define BS_  16384  // BB*SS
#define CHK  64     // timesteps per chunk
#define NCHK 4

// ---------------------------------------------------------------------------
// K1: embedding gather + max-norm renorm.  one block per (b,s) row, 128 thr.
// ---------------------------------------------------------------------------
__global__ void k_embed(const int* __restrict__ x, const float* __restrict__ emb,
                        float* __restrict__ e) {
    int row = blockIdx.x;
    int tok = x[row];
    const float* src = emb + (size_t)tok * ED;
    float* dst = e + (size_t)row * EDP;
    int tid = threadIdx.x;  // 128
    float v[3];
    float ss = 0.f;
#pragma unroll
    for (int i = 0; i < 3; ++i) {
        int k = tid + i * 128;
        float t = (k < ED) ? src[k] : 0.f;
        v[i] = t;
        ss += t * t;
    }
    for (int off = 32; off > 0; off >>= 1) ss += __shfl_xor(ss, off, 64);
    __shared__ float red[2];
    if ((tid & 63) == 0) red[tid >> 6] = ss;
    __syncthreads();
    float nrm = sqrtf(red[0] + red[1]);
    float scale = fminf(1.0f, 5.0f / (nrm + 1e-7f));
#pragma unroll
    for (int i = 0; i < 3; ++i) {
        int k = tid + i * 128;
        if (k < EDP) dst[k] = (k < ED) ? v[i] * scale : 0.f;
    }
}

// ---------------------------------------------------------------------------
// kq schedule shared by both packs and both GRU kernels:
//  m = 0,1   : kq = oc*16 + 2*ks + m            (own-unit quads, phase A)
//  m = 2..15 : kq = (oc*16 + 16 + ks*14 + (m-2)) & 127
// ---------------------------------------------------------------------------
__host__ __device__ __forceinline__ int kq_of(int oc, int ks, int m) {
    return (m < 2) ? (oc * 16 + 2 * ks + m)
                   : ((oc * 16 + 16 + ks * 14 + (m - 2)) & 127);
}

// ---------------------------------------------------------------------------
// K_prep_all: one launch builds every preprocessed weight buffer.
//  seg0: Wtc[EDP][3072]  = [Wihf^T | Wihb^T]  (rows 300..303 zero)
//  seg1: bcc[3072]       = [bihf | bihb]
//  seg2: W1at[1024][256] = W1[:, :1024]^T
//  seg3: Wq  (both dirs) = round-14 2-row streaming pack
//        per-dir [oc][m 0..15][t 0..767][p 0..1][e]; rr=2*(t>>3)+p
//  seg4: Wq2 (both dirs) = register-resident pack
//        per-dir [oc][m 0..15][g 0..2][t 0..511][e]; u=t>>3, ks=t&7
// ---------------------------------------------------------------------------
#define PN0 933888            // 304*3072
#define PN1 (PN0 + 3072)
#define PN2 (PN1 + 262144)
#define PN3 (PN2 + 1572864)   // + oct pack
#define PN4 (PN3 + 1572864)   // + reg pack

__global__ void k_prep_all(const float* __restrict__ Wihf, const float* __restrict__ Wihb,
                           const float* __restrict__ bihf, const float* __restrict__ bihb,
                           const float* __restrict__ W1,
                           const float* __restrict__ Whhf, const float* __restrict__ Whhb,
                           float* __restrict__ Wtc, float* __restrict__ bcc,
                           float* __restrict__ W1at, float* __restrict__ Wq,
                           float* __restrict__ Wq2) {
    int idx = blockIdx.x * blockDim.x + threadIdx.x;
    int stride = gridDim.x * blockDim.x;
    for (int i = idx; i < PN4; i += stride) {
        if (i < PN0) {
            int k = i / 3072, n = i - k * 3072;
            int dir = n >= 1536, nn = n - dir * 1536;
            const float* Wih = dir ? Wihb : Wihf;
            Wtc[i] = (k < ED) ? Wih[(size_t)nn * ED + k] : 0.f;
        } else if (i < PN1) {
            int j = i - PN0;
            bcc[j] = (j < 1536) ? bihf[j] : bihb[j - 1536];
        } else if (i < PN2) {
            int j = i - PN1;
            int n = j >> 10, k = j & 1023;
            W1at[(size_t)k * ATT_ + n] = W1[(size_t)n * 2048 + k];
        } else if (i < PN3) {
            int j = i - PN2;
            int dir = j / 786432, jj = j - dir * 786432;
            const float* Whh = dir ? Whhb : Whhf;
            int oc  = jj / 98304;
            int rem = jj - oc * 98304;
            int m   = rem / 6144;          // 768*2*4
            int r3  = rem - m * 6144;
            int t   = r3 >> 3;
            int p   = (r3 >> 2) & 1;
            int e   = r3 & 3;
            int ks8 = t & 7;
            int rr  = 2 * (t >> 3) + p;
            int g   = rr >> 6;
            int ul  = rr & 63;
            int u   = oc * 64 + ul;
            int kq  = kq_of(oc, ks8, m);
            Wq[j] = Whh[((size_t)(g * 512 + u)) * 512 + kq * 4 + e];
        } else {
            int j = i - PN3;
            int dir = j / 786432, jj = j - dir * 786432;
            const float* Whh = dir ? Whhb : Whhf;
            int oc  = jj / 98304;
            int rem = jj - oc * 98304;
            int m   = rem / 6144;          // 3*512*4
            int r3  = rem - m * 6144;
            int g   = r3 / 2048;           // 512*4
            int r4  = r3 - g * 2048;
            int t   = r4 >> 2;
            int e   = r4 & 3;
            int u   = t >> 3;
            int ks  = t & 7;
            int kq  = kq_of(oc, ks, m);
            Wq2[j] = Whh[((size_t)(g * 512 + oc * 64 + u)) * 512 + kq * 4 + e];
        }
    }
}

// ---------------------------------------------------------------------------
// fp32 GEMM, 128x128 tile, 256 threads, 8x8 per thread (round-12, proven).
// ---------------------------------------------------------------------------
#define BSKEW(n) ((n) + (((n) >> 5) << 2))

template <int KT, int EPI>
__global__ void __launch_bounds__(256) k_gemm128(
    const float* __restrict__ A, int lda, long strideA,
    const float* __restrict__ Bm, int ldb, long strideB,
    float* __restrict__ C, int ldc, long strideC,
    int M, int N, int K,
    const float* __restrict__ bias, const float* __restrict__ bias2,
    int spos0, int spos1) {
    __shared__ float As[KT * 132];
    __shared__ float Bs[KT * 144];
    const int tid = threadIdx.x;
    const int tx = tid & 15, ty = tid >> 4;
    const int mbase = blockIdx.y * 128, nbase = blockIdx.x * 128;
    const int spos = (spos0 >= 0 && nbase >= 1536) ? spos1 : spos0;
    const float* Ab = A + (long)blockIdx.z * strideA;
    const float* Bb = Bm + (long)blockIdx.z * strideB;
    float* Cb = C + (long)blockIdx.z * strideC;
    float acc[8][8] = {};
    const int bgrp = tx * 8 + ((tx >> 2) << 2);
    for (int k0 = 0; k0 < K; k0 += KT) {
#pragma unroll
        for (int t = 0; t < 2; ++t) {          // A: 512 float4s, 2/thread
            int f = tid * 2 + t;
            int r = f >> 2, c4 = f & 3;
            int row = mbase + r;
            int arow = (spos >= 0) ? ((row >> 6) * 256 + spos + (row & 63)) : row;
            float4 a = *(const float4*)&Ab[(size_t)arow * lda + k0 + c4 * 4];
            As[(c4 * 4 + 0) * 132 + r] = a.x;
            As[(c4 * 4 + 1) * 132 + r] = a.y;
            As[(c4 * 4 + 2) * 132 + r] = a.z;
            As[(c4 * 4 + 3) * 132 + r] = a.w;
        }
#pragma unroll
        for (int t = 0; t < 2; ++t) {          // B: 512 float4s, 2/thread
            int f = tid * 2 + t;
            int kk = f >> 5, n = (f & 31) * 4;
            float4 b = *(const float4*)&Bb[(size_t)(k0 + kk) * ldb + nbase + n];
            *(float4*)&Bs[kk * 144 + BSKEW(n)] = b;
        }
        __syncthreads();
#pragma unroll
        for (int kk = 0; kk < KT; ++kk) {
            const float4* pa = (const float4*)&As[kk * 132 + ty * 8];
            float4 a0 = pa[0], a1 = pa[1];
            const float4* pb = (const float4*)&Bs[kk * 144 + bgrp];
            float4 b0 = pb[0], b1 = pb[1];
            float av[8] = {a0.x, a0.y, a0.z, a0.w, a1.x, a1.y, a1.z, a1.w};
            float bv[8] = {b0.x, b0.y, b0.z, b0.w, b1.x, b1.y, b1.z, b1.w};
#pragma unroll
            for (int i = 0; i < 8; ++i)
#pragma unroll
                for (int j = 0; j < 8; ++j) acc[i][j] += av[i] * bv[j];
        }
        __syncthreads();
    }
    if (EPI == 3) {
        const int row0 = mbase + ty * 8;
        const size_t bb = (size_t)(row0 >> 8) * strideC;
#pragma unroll
        for (int j = 0; j < 8; ++j) {
            int col = nbase + tx * 8 + j;
            float vj[8];
#pragma unroll
            for (int i = 0; i < 8; ++i) {
                int row = row0 + i;
                vj[i] = tanhf(acc[i][j] + bias2[(size_t)(row >> 8) * ATT_ + col]);
            }
            float* cp = &Cb[bb + (size_t)col * ldc + (row0 & 255)];
            ((float4*)cp)[0] = make_float4(vj[0], vj[1], vj[2], vj[3]);
            ((float4*)cp)[1] = make_float4(vj[4], vj[5], vj[6], vj[7]);
        }
    } else {
#pragma unroll
        for (int i = 0; i < 8; ++i) {
            int row = mbase + ty * 8 + i;
            float vout[8];
#pragma unroll
            for (int j = 0; j < 8; ++j) {
                int col = nbase + tx * 8 + j;
                float v = acc[i][j];
                if (EPI == 1) v += bias[col];
                if (EPI == 2) v = tanhf(v + bias2[(size_t)(row >> 8) * ATT_ + col]);
                vout[j] = v;
            }
            float4* cp = (float4*)&Cb[(size_t)row * ldc + nbase + tx * 8];
            cp[0] = make_float4(vout[0], vout[1], vout[2], vout[3]);
            cp[1] = make_float4(vout[4], vout[5], vout[6], vout[7]);
        }
    }
}

// ---------------------------------------------------------------------------
// GRU helpers
// ---------------------------------------------------------------------------
__device__ __forceinline__ float sigmoidf_(float v) { return 1.f / (1.f + expf(-v)); }

// ===== round-14 streaming kernel (proven 633 us/chunk): 2 rows/thread =====
#define GFMA(kqv)                                                           \
    {                                                                       \
        const int kv = (kqv);                                               \
        float4 h0 = hs4[kv];                                                \
        float4 h1 = hs4[128 + kv];                                          \
        float4 h2 = hs4[256 + kv];                                          \
        float4 h3 = hs4[384 + kv];                                          \
        float4 w0 = wpm[0], w1 = wpm[1];                                    \
        wpm += 1536;                                                        \
        a00 += h0.x * w0.x + h0.y * w0.y + h0.z * w0.z + h0.w * w0.w;       \
        a01 += h1.x * w0.x + h1.y * w0.y + h1.z * w0.z + h1.w * w0.w;       \
        a02 += h2.x * w0.x + h2.y * w0.y + h2.z * w0.z + h2.w * w0.w;       \
        a03 += h3.x * w0.x + h3.y * w0.y + h3.z * w0.z + h3.w * w0.w;       \
        a10 += h0.x * w1.x + h0.y * w1.y + h0.z * w1.z + h0.w * w1.w;       \
        a11 += h1.x * w1.x + h1.y * w1.y + h1.z * w1.z + h1.w * w1.w;       \
        a12 += h2.x * w1.x + h2.y * w1.y + h2.z * w1.z + h2.w * w1.w;       \
        a13 += h3.x * w1.x + h3.y * w1.y + h3.z * w1.z + h3.w * w1.w;       \
    }

__global__ void __launch_bounds__(768)
k_gru_oct(const float* __restrict__ xw, const float* __restrict__ Wq,
          const float* __restrict__ bhhf, const float* __restrict__ bhhb,
          float* __restrict__ h_all, float* __restrict__ hx,
          unsigned* __restrict__ flg, int c) {
    const int bid   = blockIdx.x;
    const int group = bid >> 4;
    const int dir   = (bid >> 3) & 1;
    const int oc    = bid & 7;
    const int tid   = threadIdx.x;
    const float* __restrict__ bhh = dir ? bhhb : bhhf;
    const float4* __restrict__ wp =
        (const float4*)Wq + (size_t)(dir * 8 + oc) * 24576 + tid * 2;
    __shared__ __align__(16) float hs[2048];
    __shared__ float gact[768];

    if (c == 0) {
        for (int t = tid; t < 2048; t += 768) hs[t] = 0.f;
    } else {
        const int prevpos = dir ? (256 - CHK * c) : (CHK * c - 1);
        for (int t = tid; t < 2048; t += 768) {
            int bb = t >> 9, uu = t & 511;
            hs[t] = h_all[((size_t)(group * 4 + bb) * 256 + prevpos) * 1024 +
                          dir * 512 + uu];
        }
    }
    const int ks8 = tid & 7;
    const int rp  = tid >> 3;
    const int bbg = tid >> 6;
    const int ulg = tid & 63;
    const int ug  = oc * 64 + ulg;
    float b0 = 0.f, b1 = 0.f, b2 = 0.f;
    if (tid < 256) { b0 = bhh[ug]; b1 = bhh[512 + ug]; b2 = bhh[1024 + ug]; }
    const int fbase = (dir * 16 + group) * 8;
    const int fi = (fbase + oc) * 32;
    const int kqA = oc * 16 + 2 * ks8;
    const int kqB0 = (oc * 16 + 16 + ks8 * 14) & 127;
    __syncthreads();
    const float4* __restrict__ hs4 = (const float4*)hs;

    for (int j = 0; j < CHK; ++j) {
        const int gi  = c * CHK + j;
        const int pos = dir ? (255 - gi) : gi;
        float ph0 = 0.f, ph1 = 0.f, ph2 = 0.f;
        if (j > 0) {
            if (tid < 7) {
                const unsigned* f = &flg[(fbase + ((oc + 1 + tid) & 7)) * 32];
                while (__hip_atomic_load(f, __ATOMIC_RELAXED,
                                         __HIP_MEMORY_SCOPE_AGENT) < (unsigned)gi)
                    __builtin_amdgcn_s_sleep(1);
            }
            __syncthreads();
            const float* hxb = hx + (((size_t)((gi - 1) & 1) * 2 + dir) * 16 +
                                     group) * 2048;
            {
                int i0 = tid;
                int bb = i0 / 448, pi = i0 - bb * 448;
                int pu = pi + ((pi >= oc * 64) ? 64 : 0);
                ph0 = __hip_atomic_load(&hxb[bb * 512 + pu], __ATOMIC_RELAXED,
                                        __HIP_MEMORY_SCOPE_AGENT);
                int i1 = tid + 768;
                bb = i1 / 448; pi = i1 - bb * 448;
                pu = pi + ((pi >= oc * 64) ? 64 : 0);
                ph1 = __hip_atomic_load(&hxb[bb * 512 + pu], __ATOMIC_RELAXED,
                                        __HIP_MEMORY_SCOPE_AGENT);
                if (tid < 256) {
                    int i2 = tid + 1536;
                    bb = i2 / 448; pi = i2 - bb * 448;
                    pu = pi + ((pi >= oc * 64) ? 64 : 0);
                    ph2 = __hip_atomic_load(&hxb[bb * 512 + pu], __ATOMIC_RELAXED,
                                            __HIP_MEMORY_SCOPE_AGENT);
                }
            }
        }
        float xr = 0.f, xz = 0.f, xn = 0.f;
        if (tid < 256) {
            const int b = group * 4 + bbg;
            const int crow = b * CHK + (dir ? (CHK - 1 - j) : j);
            const float* __restrict__ xrow = xw + (size_t)crow * 3072 + dir * 1536;
            xr = xrow[ug]; xz = xrow[512 + ug]; xn = xrow[1024 + ug];
        }
        if (gi > 0) {
            float a00 = 0.f, a01 = 0.f, a02 = 0.f, a03 = 0.f;
            float a10 = 0.f, a11 = 0.f, a12 = 0.f, a13 = 0.f;
            const float4* wpm = wp;
            if (j > 0) {
                GFMA(kqA); GFMA(kqA + 1);
                {
                    int i0 = tid;
                    int bb = i0 / 448, pi = i0 - bb * 448;
                    int pu = pi + ((pi >= oc * 64) ? 64 : 0);
                    hs[bb * 512 + pu] = ph0;
                    int i1 = tid + 768;
                    bb = i1 / 448; pi = i1 - bb * 448;
                    pu = pi + ((pi >= oc * 64) ? 64 : 0);
                    hs[bb * 512 + pu] = ph1;
                    if (tid < 256) {
                        int i2 = tid + 1536;
                        bb = i2 / 448; pi = i2 - bb * 448;
                        pu = pi + ((pi >= oc * 64) ? 64 : 0);
                        hs[bb * 512 + pu] = ph2;
                    }
                }
                __syncthreads();
                int kq = kqB0;
#pragma unroll 7
                for (int m = 2; m < 16; ++m) { GFMA(kq); kq = (kq + 1) & 127; }
            } else {
                GFMA(kqA); GFMA(kqA + 1);
                int kq = kqB0;
#pragma unroll 7
                for (int m = 2; m < 16; ++m) { GFMA(kq); kq = (kq + 1) & 127; }
            }
            a00 += __shfl_xor(a00, 1, 64); a00 += __shfl_xor(a00, 2, 64); a00 += __shfl_xor(a00, 4, 64);
            a01 += __shfl_xor(a01, 1, 64); a01 += __shfl_xor(a01, 2, 64); a01 += __shfl_xor(a01, 4, 64);
            a02 += __shfl_xor(a02, 1, 64); a02 += __shfl_xor(a02, 2, 64); a02 += __shfl_xor(a02, 4, 64);
            a03 += __shfl_xor(a03, 1, 64); a03 += __shfl_xor(a03, 2, 64); a03 += __shfl_xor(a03, 4, 64);
            a10 += __shfl_xor(a10, 1, 64); a10 += __shfl_xor(a10, 2, 64); a10 += __shfl_xor(a10, 4, 64);
            a11 += __shfl_xor(a11, 1, 64); a11 += __shfl_xor(a11, 2, 64); a11 += __shfl_xor(a11, 4, 64);
            a12 += __shfl_xor(a12, 1, 64); a12 += __shfl_xor(a12, 2, 64); a12 += __shfl_xor(a12, 4, 64);
            a13 += __shfl_xor(a13, 1, 64); a13 += __shfl_xor(a13, 2, 64); a13 += __shfl_xor(a13, 4, 64);
            if (ks8 == 0) {
                const int r0 = 2 * rp, r1 = 2 * rp + 1;
                gact[r0] = a00;        gact[r1] = a10;
                gact[192 + r0] = a01;  gact[192 + r1] = a11;
                gact[384 + r0] = a02;  gact[384 + r1] = a12;
                gact[576 + r0] = a03;  gact[576 + r1] = a13;
            }
        }
        __syncthreads();
        if (tid < 256) {
            float hr = (gi > 0) ? gact[bbg * 192 + ulg] : 0.f;
            float hz = (gi > 0) ? gact[bbg * 192 + 64 + ulg] : 0.f;
            float hn = (gi > 0) ? gact[bbg * 192 + 128 + ulg] : 0.f;
            float rr = sigmoidf_(xr + b0 + hr);
            float zz = sigmoidf_(xz + b1 + hz);
            float nn = tanhf(xn + rr * (b2 + hn));
            float h = (1.f - zz) * nn + zz * hs[bbg * 512 + ug];
            hs[bbg * 512 + ug] = h;
            const int b = group * 4 + bbg;
            __hip_atomic_store(&h_all[((size_t)b * 256 + pos) * 1024 +
                                      dir * 512 + ug],
                               h, __ATOMIC_RELAXED, __HIP_MEMORY_SCOPE_AGENT);
            __hip_atomic_store(&hx[(((size_t)(gi & 1) * 2 + dir) * 16 + group) *
                                       2048 + bbg * 512 + ug],
                               h, __ATOMIC_RELAXED, __HIP_MEMORY_SCOPE_AGENT);
        }
        __syncthreads();
        if (tid == 0)
            __hip_atomic_store(&flg[fi], (unsigned)(gi + 1), __ATOMIC_RELEASE,
                               __HIP_MEMORY_SCOPE_AGENT);
    }
}

// ===== register-resident kernel (round-15 math, now with occupancy waiver) =====
#define RFMA(mm, kv)                                                        \
    {                                                                       \
        float4 h0 = hs4[kv];                                                \
        float4 h1 = hs4[128 + (kv)];                                        \
        float4 h2 = hs4[256 + (kv)];                                        \
        float4 h3 = hs4[384 + (kv)];                                        \
        float4 w = wreg[(mm) * 3 + 0];                                      \
        a0[0] += h0.x*w.x + h0.y*w.y + h0.z*w.z + h0.w*w.w;                 \
        a0[1] += h1.x*w.x + h1.y*w.y + h1.z*w.z + h1.w*w.w;                 \
        a0[2] += h2.x*w.x + h2.y*w.y + h2.z*w.z + h2.w*w.w;                 \
        a0[3] += h3.x*w.x + h3.y*w.y + h3.z*w.z + h3.w*w.w;                 \
        w = wreg[(mm) * 3 + 1];                                             \
        a1[0] += h0.x*w.x + h0.y*w.y + h0.z*w.z + h0.w*w.w;                 \
        a1[1] += h1.x*w.x + h1.y*w.y + h1.z*w.z + h1.w*w.w;                 \
        a1[2] += h2.x*w.x + h2.y*w.y + h2.z*w.z + h2.w*w.w;                 \
        a1[3] += h3.x*w.x + h3.y*w.y + h3.z*w.z + h3.w*w.w;                 \
        w = wreg[(mm) * 3 + 2];                                             \
        a2[0] += h0.x*w.x + h0.y*w.y + h0.z*w.z + h0.w*w.w;                 \
        a2[1] += h1.x*w.x + h1.y*w.y + h1.z*w.z + h1.w*w.w;                 \
        a2[2] += h2.x*w.x + h2.y*w.y + h2.z*w.z + h2.w*w.w;                 \
        a2[3] += h3.x*w.x + h3.y*w.y + h3.z*w.z + h3.w*w.w;                 \
    }

__global__ void __launch_bounds__(512, 2)
k_gru_reg(const float* __restrict__ xw, const float* __restrict__ Wq2,
          const float* __restrict__ bhhf, const float* __restrict__ bhhb,
          float* __restrict__ h_all, float* __restrict__ hx,
          unsigned* __restrict__ flg, int c) {
    const int bid   = blockIdx.x;
    const int group = bid >> 4;
    const int dir   = (bid >> 3) & 1;
    const int oc    = bid & 7;
    const int tid   = threadIdx.x;     // 512
    const int u     = tid >> 3;
    const int ks    = tid & 7;
    const int ug    = oc * 64 + u;
    const float* __restrict__ bhh = dir ? bhhb : bhhf;
    __shared__ __align__(16) float hs[2048];

    const float4* __restrict__ wp =
        (const float4*)Wq2 + (size_t)(dir * 8 + oc) * 24576 + tid;
    float4 wreg[48];
#pragma unroll
    for (int i = 0; i < 48; ++i) wreg[i] = wp[(size_t)i * 512];

    if (c == 0) {
        for (int t = tid; t < 2048; t += 512) hs[t] = 0.f;
    } else {
        const int prevpos = dir ? (256 - CHK * c) : (CHK * c - 1);
        for (int t = tid; t < 2048; t += 512) {
            int bb = t >> 9, uu = t & 511;
            hs[t] = h_all[((size_t)(group * 4 + bb) * 256 + prevpos) * 1024 +
                          dir * 512 + uu];
        }
    }
    float b0 = 0.f, b1 = 0.f, b2 = 0.f;
    if (ks == 0) { b0 = bhh[ug]; b1 = bhh[512 + ug]; b2 = bhh[1024 + ug]; }
    const int fbase = (dir * 16 + group) * 8;
    const int fi = (fbase + oc) * 32;
    __syncthreads();
    const float4* __restrict__ hs4 = (const float4*)hs;

    for (int j = 0; j < CHK; ++j) {
        const int gi  = c * CHK + j;
        const int pos = dir ? (255 - gi) : gi;
        float ph0 = 0.f, ph1 = 0.f, ph2 = 0.f, ph3 = 0.f;
        if (j > 0) {
            if (tid < 7) {
                const unsigned* f = &flg[(fbase + ((oc + 1 + tid) & 7)) * 32];
                while (__hip_atomic_load(f, __ATOMIC_RELAXED,
                                         __HIP_MEMORY_SCOPE_AGENT) < (unsigned)gi)
                    __builtin_amdgcn_s_sleep(1);
            }
            __syncthreads();
            const float* hxb = hx + (((size_t)((gi - 1) & 1) * 2 + dir) * 16 +
                                     group) * 2048;
            {
                int i0 = tid;
                int bb = i0 / 448, pi = i0 - bb * 448;
                int pu = pi + ((pi >= oc * 64) ? 64 : 0);
                ph0 = __hip_atomic_load(&hxb[bb * 512 + pu], __ATOMIC_RELAXED,
                                        __HIP_MEMORY_SCOPE_AGENT);
                int i1 = tid + 512;
                bb = i1 / 448; pi = i1 - bb * 448;
                pu = pi + ((pi >= oc * 64) ? 64 : 0);
                ph1 = __hip_atomic_load(&hxb[bb * 512 + pu], __ATOMIC_RELAXED,
                                        __HIP_MEMORY_SCOPE_AGENT);
                int i2 = tid + 1024;
                bb = i2 / 448; pi = i2 - bb * 448;
                pu = pi + ((pi >= oc * 64) ? 64 : 0);
                ph2 = __hip_atomic_load(&hxb[bb * 512 + pu], __ATOMIC_RELAXED,
                                        __HIP_MEMORY_SCOPE_AGENT);
                if (tid < 256) {
                    int i3 = tid + 1536;
                    bb = i3 / 448; pi = i3 - bb * 448;
                    pu = pi + ((pi >= oc * 64) ? 64 : 0);
                    ph3 = __hip_atomic_load(&hxb[bb * 512 + pu], __ATOMIC_RELAXED,
                                            __HIP_MEMORY_SCOPE_AGENT);
                }
            }
        }
        float a0[4] = {0.f, 0.f, 0.f, 0.f};
        float a1[4] = {0.f, 0.f, 0.f, 0.f};
        float a2[4] = {0.f, 0.f, 0.f, 0.f};
        if (gi > 0) {
            if (j > 0) {
                RFMA(0, oc * 16 + 2 * ks);
                RFMA(1, oc * 16 + 2 * ks + 1);
                {
                    int i0 = tid;
                    int bb = i0 / 448, pi = i0 - bb * 448;
                    int pu = pi + ((pi >= oc * 64) ? 64 : 0);
                    hs[bb * 512 + pu] = ph0;
                    int i1 = tid + 512;
                    bb = i1 / 448; pi = i1 - bb * 448;
                    pu = pi + ((pi >= oc * 64) ? 64 : 0);
                    hs[bb * 512 + pu] = ph1;
                    int i2 = tid + 1024;
                    bb = i2 / 448; pi = i2 - bb * 448;
                    pu = pi + ((pi >= oc * 64) ? 64 : 0);
                    hs[bb * 512 + pu] = ph2;
                    if (tid < 256) {
                        int i3 = tid + 1536;
                        bb = i3 / 448; pi = i3 - bb * 448;
                        pu = pi + ((pi >= oc * 64) ? 64 : 0);
                        hs[bb * 512 + pu] = ph3;
                    }
                }
                __syncthreads();
                int kq = (oc * 16 + 16 + ks * 14) & 127;
#pragma unroll
                for (int m = 2; m < 16; ++m) { RFMA(m, kq); kq = (kq + 1) & 127; }
            } else {
                RFMA(0, oc * 16 + 2 * ks);
                RFMA(1, oc * 16 + 2 * ks + 1);
                int kq = (oc * 16 + 16 + ks * 14) & 127;
#pragma unroll
                for (int m = 2; m < 16; ++m) { RFMA(m, kq); kq = (kq + 1) & 127; }
            }
#pragma unroll
            for (int bb = 0; bb < 4; ++bb) {
                a0[bb] += __shfl_xor(a0[bb], 1, 64);
                a0[bb] += __shfl_xor(a0[bb], 2, 64);
                a0[bb] += __shfl_xor(a0[bb], 4, 64);
                a1[bb] += __shfl_xor(a1[bb], 1, 64);
                a1[bb] += __shfl_xor(a1[bb], 2, 64);
                a1[bb] += __shfl_xor(a1[bb], 4, 64);
                a2[bb] += __shfl_xor(a2[bb], 1, 64);
                a2[bb] += __shfl_xor(a2[bb], 2, 64);
                a2[bb] += __shfl_xor(a2[bb], 4, 64);
            }
        }
        __syncthreads();
        if (ks == 0) {
#pragma unroll
            for (int bb = 0; bb < 4; ++bb) {
                const int b = group * 4 + bb;
                const int crow = b * CHK + (dir ? (CHK - 1 - j) : j);
                const float* __restrict__ xrow =
                    xw + (size_t)crow * 3072 + dir * 1536;
                float xr = xrow[ug], xz = xrow[512 + ug], xn = xrow[1024 + ug];
                float rr = sigmoidf_(xr + b0 + a0[bb]);
                float zz = sigmoidf_(xz + b1 + a1[bb]);
                float nn = tanhf(xn + rr * (b2 + a2[bb]));
                float h = (1.f - zz) * nn + zz * hs[bb * 512 + ug];
                hs[bb * 512 + ug] = h;
                __hip_atomic_store(&h_all[((size_t)b * 256 + pos) * 1024 +
                                          dir * 512 + ug],
                                   h, __ATOMIC_RELAXED, __HIP_MEMORY_SCOPE_AGENT);
                __hip_atomic_store(&hx[(((size_t)(gi & 1) * 2 + dir) * 16 +
                                        group) * 2048 + bb * 512 + ug],
                                   h, __ATOMIC_RELAXED, __HIP_MEMORY_SCOPE_AGENT);
            }
        }
        __syncthreads();
        if (tid == 0)
            __hip_atomic_store(&flg[fi], (unsigned)(gi + 1), __ATOMIC_RELEASE,
                               __HIP_MEMORY_SCOPE_AGENT);
    }
}

// ---------------------------------------------------------------------------
// K_target_tmp2: fused span-mean + tmp2 projection.  one block per b.
// ---------------------------------------------------------------------------
__global__ void k_target_tmp2(const float* __restrict__ h_all,
                              const int* __restrict__ ts, const int* __restrict__ te,
                              const float* __restrict__ W1, const float* __restrict__ b1,
                              float* __restrict__ tmp2) {
    int b = blockIdx.x;
    int tid = threadIdx.x;  // 256
    __shared__ __align__(16) float tg[1024];
    int s0 = ts[b], s1 = te[b];
    float inv = 1.f / (float)(s1 - s0 + 1);
    for (int d = tid; d < 1024; d += 256) {
        float acc = 0.f;
        for (int s = s0; s <= s1; ++s) acc += h_all[((size_t)b * 256 + s) * 1024 + d];
        tg[d] = acc * inv;
    }
    __syncthreads();
    const float4* wrow = (const float4*)(W1 + (size_t)tid * 2048 + 1024);
    const float4* tg4 = (const float4*)tg;
    float acc = b1[tid];
    for (int k = 0; k < 256; ++k) {
        float4 w = wrow[k], t = tg4[k];
        acc += w.x * t.x + w.y * t.y + w.z * t.z + w.w * t.w;
    }
    tmp2[(size_t)b * ATT_ + tid] = acc;
}

// ---------------------------------------------------------------------------
// softmax over last axis, in place.  one block per (b,k) row of 256.
// ---------------------------------------------------------------------------
__global__ void k_softmax(float* __restrict__ beta) {
    int row = blockIdx.x;
    float* p = beta + (size_t)row * 256;
    int tid = threadIdx.x;  // 256
    float v = p[tid];
    float m = v;
    for (int off = 32; off > 0; off >>= 1) m = fmaxf(m, __shfl_xor(m, off, 64));
    __shared__ float red[4];
    if ((tid & 63) == 0) red[tid >> 6] = m;
    __syncthreads();
    m = fmaxf(fmaxf(red[0], red[1]), fmaxf(red[2], red[3]));
    float e = expf(v - m);
    float ssum = e;
    for (int off = 32; off > 0; off >>= 1) ssum += __shfl_xor(ssum, off, 64);
    __shared__ float red2[4];
    if ((tid & 63) == 0) red2[tid >> 6] = ssum;
    __syncthreads();
    float tot = red2[0] + red2[1] + red2[2] + red2[3];
    p[tid] = e / tot;
}

// ---------------------------------------------------------------------------
// final: out[row, 0:3] = result[row,:] . W2[l,:] + b2[l]
// ---------------------------------------------------------------------------
__global__ void k_final(const float* __restrict__ result, const float* __restrict__ W2,
                        const float* __restrict__ b2, float* __restrict__ out) {
    int row = blockIdx.x;
    int tid = threadIdx.x;  // 256
    const float* r = result + (size_t)row * 1024;
    float a0 = 0.f, a1 = 0.f, a2 = 0.f;
    for (int h = tid; h < 1024; h += 256) {
        float rv = r[h];
        a0 += rv * W2[h];
        a1 += rv * W2[1024 + h];
        a2 += rv * W2[2048 + h];
    }
    for (int off = 32; off > 0; off >>= 1) {
        a0 += __shfl_xor(a0, off, 64);
        a1 += __shfl_xor(a1, off, 64);
        a2 += __shfl_xor(a2, off, 64);
    }
    __shared__ float red[4][3];
    if ((tid & 63) == 0) {
        red[tid >> 6][0] = a0; red[tid >> 6][1] = a1; red[tid >> 6][2] = a2;
    }
    __syncthreads();
    if (tid < 3) {
        float s = red[0][tid] + red[1][tid] + red[2][tid] + red[3][tid];
        out[(size_t)row * 3 + tid] = s + b2[tid];
    }
}

// ---------------------------------------------------------------------------
extern "C" void kernel_launch(void* const* d_in, const int* in_sizes, int n_in,
                              void* d_out, int out_size, void* d_ws, size_t ws_size,
                              hipStream_t stream) {
    const int*   x      = (const int*)d_in[0];
    const int*   tstart = (const int*)d_in[1];
    const int*   tend   = (const int*)d_in[2];
    const float* emb    = (const float*)d_in[3];
    const float* Wihf   = (const float*)d_in[4];
    const float* Whhf   = (const float*)d_in[5];
    const float* bihf   = (const float*)d_in[6];
    const float* bhhf   = (const float*)d_in[7];
    const float* Wihb   = (const float*)d_in[8];
    const float* Whhb   = (const float*)d_in[9];
    const float* bihb   = (const float*)d_in[10];
    const float* bhhb   = (const float*)d_in[11];
    const float* W1     = (const float*)d_in[12];
    const float* b1     = (const float*)d_in[13];
    const float* u      = (const float*)d_in[14];
    const float* W2     = (const float*)d_in[15];
    const float* b2     = (const float*)d_in[16];
    float* out = (float*)d_out;
    float* ws = (float*)d_ws;

    // workspace layout (floats).  total = 43,309,376 floats = 173.2 MB
    float* h_p    = ws;                        // 16,777,216
    float* e_p    = h_p + 16777216;            // 4,980,736  (16384 x 304)
    float* xwc_p  = e_p + 4980736;             // 12,582,912 (chunk, both dirs)
    float* Wq_p   = xwc_p + 12582912;          // 1,572,864  (oct pack)
    float* Wq2_p  = Wq_p + 1572864;            // 1,572,864  (reg pack)
    float* Wtc_p  = Wq2_p + 1572864;           // 933,888    (304 x 3072)
    float* pad_p  = Wtc_p + 933888;            // 200,000    (res alias headroom)
    float* bcc_p  = pad_p + 200000;            // 3,072
    float* W1at_p = bcc_p + 3072;              // 262,144
    float* tg_p   = W1at_p + 262144;           // 65,536  (reserved)
    float* t2_p   = tg_p + 65536;              // 16,384
    float* beta_p = t2_p + 16384;              // 4,194,304
    float* hx_p   = beta_p + 4194304;          // 131,072
    unsigned* flg_p = (unsigned*)(hx_p + 131072);  // 16,384 uints
    // aliases into dead-after-GRU regions:
    float* ot_p   = e_p;                       // 4,194,304 <= 4,980,736
    float* res_p  = xwc_p;                     // 16,777,216 <= xwc..pad (16,862,528)

    if (ws_size < (size_t)43309376 * 4) return;  // refuse to overflow scratch

    // choose GRU kernel: register-resident if the compiler kept wreg in VGPRs
    // (no scratch); otherwise the proven round-14 streaming kernel.
    // Host-side attribute query: deterministic, no stream ops (capture-safe).
    bool useReg = false;
    {
        hipFuncAttributes attr;
        if (hipFuncGetAttributes(&attr, (const void*)k_gru_reg) == hipSuccess)
            useReg = (attr.localSizeBytes == 0);
    }

    // 0. zero pair flags (every call / graph replay)
    hipMemsetAsync(flg_p, 0, 16384 * sizeof(unsigned), stream);
    // 1. embedding + renorm (padded to 304 cols)
    k_embed<<<BS_, 128, 0, stream>>>(x, emb, e_p);
    // 2. all weight preps in one launch (both GRU packs)
    k_prep_all<<<1024, 256, 0, stream>>>(Wihf, Wihb, bihf, bihb, W1, Whhf, Whhb,
                                         Wtc_p, bcc_p, W1at_p, Wq_p, Wq2_p);
    // 3. chunked: merged 2-dir input proj, then GRU
    for (int c = 0; c < NCHK; ++c) {
        k_gemm128<16, 1><<<dim3(24, 32, 1), 256, 0, stream>>>(
            e_p, EDP, 0, Wtc_p, 3072, 0, xwc_p, 3072, 0, BB * CHK, 3072, EDP,
            bcc_p, nullptr, CHK * c, 192 - CHK * c);
        if (useReg)
            k_gru_reg<<<256, 512, 0, stream>>>(xwc_p, Wq2_p, bhhf, bhhb,
                                               h_p, hx_p, flg_p, c);
        else
            k_gru_oct<<<256, 768, 0, stream>>>(xwc_p, Wq_p, bhhf, bhhb,
                                               h_p, hx_p, flg_p, c);
    }
    // 4. fused target span mean + tmp2
    k_target_tmp2<<<BB, 256, 0, stream>>>(h_p, tstart, tend, W1, b1, t2_p);
    // 5. o = tanh(h @ W1a^T + tmp2), written TRANSPOSED into ot[b][a][s]
    k_gemm128<16, 3><<<dim3(2, 128, 1), 256, 0, stream>>>(
        h_p, 1024, 0, W1at_p, ATT_, 0, ot_p, ATT_, 65536, BS_, ATT_, 1024,
        nullptr, t2_p, -1, -1);
    // 6. beta[b][k][s] = u @ ot[b]
    k_gemm128<16, 0><<<dim3(2, 2, BB), 256, 0, stream>>>(
        u, ATT_, 0, ot_p, ATT_, 65536, beta_p, ATT_, 65536, ATT_, ATT_, ATT_,
        nullptr, nullptr, -1, -1);
    // 7. softmax over s (in place)
    k_softmax<<<BS_, 256, 0, stream>>>(beta_p);
    // 8. result[b][k][h] = alfa[b] @ h[b]
    k_gemm128<16, 0><<<dim3(8, 2, BB), 256, 0, stream>>>(
        beta_p, ATT_, 65536, h_p, 1024, 262144, res_p, 1024, 262144,
        ATT_, 1024, ATT_, nullptr, nullptr, -1, -1);
    // 9. final linear
    k_final<<<BS_, 256, 0, stream>>>(res_p, W2, b2, out);
}